// Round 10
// baseline (204.526 us; speedup 1.0000x reference)
//
#include <hip/hip_runtime.h>

#define Bc 16
#define Cc 512
#define Tc 2048
#define QT 128
#define KT 64
#define PST 72    // P_lds row stride (ushort), 64+8 pad
#define LTS 66    // kqv LDS transposed-tile row stride (ushort), 64+2 pad
#define EPS 132   // epilogue LDS row stride (floats), 128+4 pad (16B-aligned)

typedef __attribute__((ext_vector_type(8))) short short8;
typedef __attribute__((ext_vector_type(4))) float f32x4;
typedef unsigned short u16;

static __device__ __forceinline__ u16 f2bf(float x) {
  unsigned u = __float_as_uint(x);
  u += 0x7FFF + ((u >> 16) & 1);   // RNE
  return (u16)(u >> 16);
}

// Pack 2 f32 -> 2 bf16 in one VALU op (no builtin on gfx950).
static __device__ __forceinline__ unsigned cvt_pk_bf16(float lo, float hi) {
  unsigned r;
  asm("v_cvt_pk_bf16_f32 %0, %1, %2" : "=v"(r) : "v"(lo), "v"(hi));
  return r;
}

// Barrier that waits ONLY on LDS ops (lgkmcnt) — outstanding global loads
// stay in flight across it.
static __device__ __forceinline__ void block_sync_lds() {
  __builtin_amdgcn_sched_barrier(0);
  asm volatile("s_waitcnt lgkmcnt(0)" ::: "memory");
  __builtin_amdgcn_s_barrier();
  __builtin_amdgcn_sched_barrier(0);
}

// ---------------- Kernel 0: W -> bf16 (fused k||q), bias -> bkq ----------------
__global__ __launch_bounds__(256) void prep_kernel(
    const float* __restrict__ Wk, const float* __restrict__ Wq,
    const float* __restrict__ bk, const float* __restrict__ bq,
    u16* __restrict__ Wbf, float* __restrict__ bkq)
{
  int idx  = blockIdx.x * 256 + threadIdx.x;
  int base = idx * 4;
  if (base < 128 * Cc) {
    int ch = base >> 9;
    int c  = base & (Cc - 1);
    const float* src = (ch < 64) ? (Wk + (size_t)ch * Cc + c)
                                 : (Wq + (size_t)(ch - 64) * Cc + c);
    f32x4 w = *reinterpret_cast<const f32x4*>(src);
    uint2 o;
    o.x = (unsigned)f2bf(w[0]) | ((unsigned)f2bf(w[1]) << 16);
    o.y = (unsigned)f2bf(w[2]) | ((unsigned)f2bf(w[3]) << 16);
    *reinterpret_cast<uint2*>(Wbf + base) = o;
  }
  if (idx < 128) bkq[idx] = (idx < 64) ? bk[idx] : bq[idx - 64];
}

// ---------------- Kernel 1: kq[t][ch] via MFMA + vbf16 emission ----------------
__global__ __launch_bounds__(256) void kqv_kernel(
    const float* __restrict__ v, const u16* __restrict__ Wbf,
    const float* __restrict__ bkq, u16* __restrict__ kq, u16* __restrict__ vbf)
{
  __shared__ u16 LDSt[2][64][LTS];   // [buf][t][c] transposed bf16 tile
  const int b   = blockIdx.y;
  const int t0  = blockIdx.x * 64;
  const int tid = threadIdx.x;
  const int lane = tid & 63;
  const int w    = tid >> 6;     // 0..3
  const int l15  = lane & 15;
  const int lg   = lane >> 4;

  f32x4 acc[8];
  #pragma unroll
  for (int mt = 0; mt < 8; ++mt) acc[mt] = f32x4{0.f, 0.f, 0.f, 0.f};

  const float* vb = v + (size_t)b * Cc * Tc + t0;
  float x[16];
  #pragma unroll
  for (int r = 0; r < 16; ++r) x[r] = vb[(size_t)(w * 16 + r) * Tc + lane];

  int buf = 0;
  for (int c0 = 0; c0 < Cc; c0 += 64, buf ^= 1) {
    #pragma unroll
    for (int r = 0; r < 16; ++r) {
      u16 hb = f2bf(x[r]);
      LDSt[buf][lane][w * 16 + r] = hb;
      vbf[((size_t)b * Cc + c0 + w * 16 + r) * Tc + t0 + lane] = hb;
    }
    block_sync_lds();
    if (c0 + 64 < Cc) {
      #pragma unroll
      for (int r = 0; r < 16; ++r)
        x[r] = vb[(size_t)(c0 + 64 + w * 16 + r) * Tc + lane];
    }
    #pragma unroll
    for (int ks = 0; ks < 2; ++ks) {
      short8 bfrag = *reinterpret_cast<const short8*>(&LDSt[buf][w * 16 + l15][ks * 32 + lg * 8]);
      #pragma unroll
      for (int mt = 0; mt < 8; ++mt) {
        short8 afrag = *reinterpret_cast<const short8*>(
            Wbf + (size_t)(mt * 16 + l15) * Cc + c0 + ks * 32 + lg * 8);
        acc[mt] = __builtin_amdgcn_mfma_f32_16x16x32_bf16(afrag, bfrag, acc[mt], 0, 0, 0);
      }
    }
  }
  const int t = t0 + w * 16 + l15;
  u16* op = kq + ((size_t)b * Tc + t) * 128;
  #pragma unroll
  for (int mt = 0; mt < 8; ++mt) {
    int chb = mt * 16 + lg * 4;
    uint2 o;
    o.x = cvt_pk_bf16(acc[mt][0] + bkq[chb + 0], acc[mt][1] + bkq[chb + 1]);
    o.y = cvt_pk_bf16(acc[mt][2] + bkq[chb + 2], acc[mt][3] + bkq[chb + 3]);
    *reinterpret_cast<uint2*>(op + chb) = o;
  }
}

// ---------------- Kernel 2: flash attention, 16 waves, 4 waves/SIMD ----------------
// Same block tile (b, 128 j, all 512 c) but 16 waves: wave = (jt = wid&7, ih = wid>>3).
// S: wave computes its jt's S for i-half ih (2 16x16 tiles). PV: wave owns 32
// channels (c0 = wid*32). Per-wave O = 64 VGPR -> total regs <= 128 -> 4 waves/SIMD.
__global__ __launch_bounds__(1024, 4) void attn_kernel(
    const float* __restrict__ v, const u16* __restrict__ vbf,
    const u16* __restrict__ kq, const float* __restrict__ gamma_p,
    float* __restrict__ out)
{
  __shared__ u16 P[2][QT * PST];       // 36864 B; epilogue aliases as float
  __shared__ float lsum2[2][QT];
  __shared__ float linv_lds[QT];

  // XCD-aware swizzle: 256 blocks, 8 XCDs -> each XCD sees 2 consecutive b's
  const int L   = blockIdx.x;
  const int lin = (L & 7) * 32 + (L >> 3);
  const int b   = lin >> 4;
  const int j0  = (lin & 15) * QT;
  const int tid = threadIdx.x;
  const int lane = tid & 63;
  const int wid  = tid >> 6;      // 0..15
  const int l15  = lane & 15;
  const int lg   = lane >> 4;     // 0..3
  const int jt   = wid & 7;       // owned S j-tile
  const int ih   = wid >> 3;      // owned i-half (0: it 0-1, 1: it 2-3)
  const int c0   = wid * 32;      // owned O channel slice

  short8 qf0, qf1;
  {
    const u16* qp = kq + (size_t)(b * Tc + j0 + jt * 16 + l15) * 128 + 64 + lg * 8;
    qf0 = *reinterpret_cast<const short8*>(qp);
    qf1 = *reinterpret_cast<const short8*>(qp + 32);
  }

  f32x4 O[2][8];   // [c2][jj]  32 ch x 128 j
  #pragma unroll
  for (int a = 0; a < 2; ++a)
    #pragma unroll
    for (int bb = 0; bb < 8; ++bb) O[a][bb] = f32x4{0.f, 0.f, 0.f, 0.f};

  float lsum = 0.f;   // lane-local partial (this wave's i-half); combined at end

  const u16* kbase = kq + (size_t)b * Tc * 128 + lg * 8;
  const u16* vbase = vbf + ((size_t)b * Cc + c0) * Tc;

  int pb = 0;
  for (int i0 = 0; i0 < Tc; i0 += KT, pb ^= 1) {
    // ---- S for (jt, ih): 2 it-tiles, K loaded at use (4-wave TLP hides it) ----
    {
      f32x4 sacc[2];
      #pragma unroll
      for (int itl = 0; itl < 2; ++itl) {
        const int it = ih * 2 + itl;
        const u16* kp = kbase + (size_t)(i0 + it * 16 + l15) * 128;
        short8 af0 = *reinterpret_cast<const short8*>(kp);
        short8 af1 = *reinterpret_cast<const short8*>(kp + 32);
        f32x4 s = f32x4{0.f, 0.f, 0.f, 0.f};
        s = __builtin_amdgcn_mfma_f32_16x16x32_bf16(af0, qf0, s, 0, 0, 0);
        s = __builtin_amdgcn_mfma_f32_16x16x32_bf16(af1, qf1, s, 0, 0, 0);
        sacc[itl] = s;
      }
      // exp + pack + publish own P rows
      u16* prow = &P[pb][(jt * 16 + l15) * PST];
      #pragma unroll
      for (int itl = 0; itl < 2; ++itl) {
        const int it = ih * 2 + itl;
        float p0 = __expf(sacc[itl][0]);
        float p1 = __expf(sacc[itl][1]);
        float p2 = __expf(sacc[itl][2]);
        float p3 = __expf(sacc[itl][3]);
        lsum += (p0 + p1) + (p2 + p3);
        uint2 wv;
        wv.x = cvt_pk_bf16(p0, p1);
        wv.y = cvt_pk_bf16(p2, p3);
        *reinterpret_cast<uint2*>(prow + it * 16 + lg * 4) = wv;
      }
    }
    block_sync_lds();

    // ---- PV: issue V loads, then O[c,j] += V[c,i] P[i,j] ----
    __builtin_amdgcn_s_setprio(1);
    #pragma unroll
    for (int is = 0; is < 2; ++is) {
      short8 vf[2];
      #pragma unroll
      for (int c2 = 0; c2 < 2; ++c2)
        vf[c2] = *reinterpret_cast<const short8*>(
            vbase + (size_t)(c2 * 16 + l15) * Tc + i0 + is * 32 + lg * 8);
      short8 pf[8];
      #pragma unroll
      for (int jj = 0; jj < 8; ++jj)
        pf[jj] = *reinterpret_cast<const short8*>(
            &P[pb][(jj * 16 + l15) * PST + is * 32 + lg * 8]);
      #pragma unroll
      for (int c2 = 0; c2 < 2; ++c2)
        #pragma unroll
        for (int jj = 0; jj < 8; ++jj)
          O[c2][jj] = __builtin_amdgcn_mfma_f32_16x16x32_bf16(vf[c2], pf[jj], O[c2][jj], 0, 0, 0);
    }
    __builtin_amdgcn_s_setprio(0);
    // next iteration's S writes P[pb^1]; PV readers of P[pb] finish before the
    // barrier inside the next iteration -> single barrier per iter is race-free
  }

  // ---- denominators: combine the two i-halves per j ----
  lsum += __shfl_xor(lsum, 16);
  lsum += __shfl_xor(lsum, 32);
  if (lane < 16) lsum2[ih][jt * 16 + lane] = lsum;
  __syncthreads();
  const float gamma = *gamma_p;
  if (tid < QT) linv_lds[tid] = gamma / (lsum2[0][tid] + lsum2[1][tid]);
  __syncthreads();

  // ---- vectorized epilogue: per-wave LDS transpose (aliases P), float4 I/O ----
  // Coalesced orientation: 16 consecutive lanes share one channel row.
  float* ep = reinterpret_cast<float*>(&P[0][0]) + wid * (4 * EPS);  // 4 rows x EPS
  const int rd_jq = lane & 15;   // j-quad within row
  const int rd_cl = lane >> 4;   // row (0..3)

  #pragma unroll
  for (int r = 0; r < 8; ++r) {
    const int c2 = r >> 2;
    const int q  = r & 3;
    if (lg == q) {
      #pragma unroll
      for (int jj = 0; jj < 8; ++jj)
        #pragma unroll
        for (int rr = 0; rr < 4; ++rr)
          ep[rr * EPS + jj * 16 + l15] = O[c2][jj][rr];
    }
    asm volatile("s_waitcnt lgkmcnt(0)" ::: "memory");
    __builtin_amdgcn_sched_barrier(0);
    const int c_glob = c0 + c2 * 16 + q * 4 + rd_cl;
    const float* vrow = v + ((size_t)(b * Cc + c_glob)) * Tc + j0;
    float* orow = out + ((size_t)(b * Cc + c_glob)) * Tc + j0;
    #pragma unroll
    for (int qq = 0; qq < 2; ++qq) {
      const int jf = (rd_jq + 16 * qq) * 4;
      f32x4 o4 = *reinterpret_cast<const f32x4*>(&ep[rd_cl * EPS + jf]);
      f32x4 li = *reinterpret_cast<const f32x4*>(&linv_lds[jf]);
      f32x4 v4 = *reinterpret_cast<const f32x4*>(&vrow[jf]);
      f32x4 o;
      o[0] = v4[0] + li[0] * o4[0];
      o[1] = v4[1] + li[1] * o4[1];
      o[2] = v4[2] + li[2] * o4[2];
      o[3] = v4[3] + li[3] * o4[3];
      *reinterpret_cast<f32x4*>(&orow[jf]) = o;
    }
    asm volatile("s_waitcnt lgkmcnt(0)" ::: "memory");
    __builtin_amdgcn_sched_barrier(0);
  }
}

extern "C" void kernel_launch(void* const* d_in, const int* in_sizes, int n_in,
                              void* d_out, int out_size, void* d_ws, size_t ws_size,
                              hipStream_t stream) {
  const float* v  = (const float*)d_in[0];
  const float* Wk = (const float*)d_in[1];
  const float* bk = (const float*)d_in[2];
  const float* Wq = (const float*)d_in[3];
  const float* bq = (const float*)d_in[4];
  const float* gm = (const float*)d_in[5];
  float* out = (float*)d_out;

  char* ws = (char*)d_ws;
  u16*   kqb = (u16*)ws;                                   //  8,388,608 B
  u16*   vbf = (u16*)(ws + 8388608);                       // 33,554,432 B
  u16*   Wbf = (u16*)(ws + 8388608 + 33554432);            //    131,072 B
  float* bkq = (float*)(ws + 8388608 + 33554432 + 131072); //        512 B

  prep_kernel<<<dim3(64), dim3(256), 0, stream>>>(Wk, Wq, bk, bq, Wbf, bkq);
  kqv_kernel<<<dim3(Tc / 64, Bc), dim3(256), 0, stream>>>(v, Wbf, bkq, kqb, vbf);
  attn_kernel<<<dim3((Tc / QT) * Bc), dim3(1024), 0, stream>>>(v, vbf, kqb, gm, out);
}